// Round 3
// baseline (1573.263 us; speedup 1.0000x reference)
//
#include <hip/hip_runtime.h>
#include <hip/hip_bf16.h>

// Non-local attention block, B=8 C=256 C2=128 H=W=64 (HW=4096), pooled 32x32 (1024).
// Global tensors are FLOAT32 (per reference dtypes). Intermediates stored bf16 in scratch.
//
// Flat-reshape identities (raw buffer reinterpretations):
//   x1[b,i,j]  = y1_flat[b][i*128+j]   ([4096][128] row-major view of NCHW y1)
//   x2[b,j,k]  = p_flat [b][j*1024+k]  (natural [128][1024])
//   x3[b,k,j]  = p_flat [b][k*128+j]   ([1024][128] row-major view)
//   o4_flat[b][c*4096+hw] == O rows flat [4096][128] (attention O writes straight to NCHW)
//
// Buffers: y1 (bf16, ws @0, 4,194,304 elems; attention writes O in-place over it),
//          p (bf16, ws @4,194,304, 1,048,576 elems),
//          y2 (bf16, scratch inside d_out; dead before conv3 writes f32 output).

typedef unsigned short u16;
typedef unsigned int u32;

#define DEV static __device__ __forceinline__

DEV float bf2f(u16 v){ return __uint_as_float(((u32)v)<<16); }
DEV float bflo(u32 p){ return __uint_as_float(p<<16); }
DEV float bfhi(u32 p){ return __uint_as_float(p & 0xFFFF0000u); }
DEV u16 f2bf(float f){
  u32 x = __float_as_uint(f);
  x += 0x7FFFu + ((x>>16)&1u);   // RNE (no NaN/inf in this pipeline)
  return (u16)(x>>16);
}
DEV u32 pack2(float a, float b){ return ((u32)f2bf(a)) | (((u32)f2bf(b))<<16); }

// ---------------- K1: fused conv1 + conv2 (1x1 conv + bias + BN + ReLU), f32 in, bf16 out --------
// grid (8 px-tiles, 8 oc-tiles, 8 batches), 256 thr. Block: 512 px x 16 oc x 2 convs.
// wave wv owns oc {oc0+wv*4..+3}; lane ln owns px {2ln,2ln+1}+128k, k=0..3.
__global__ __launch_bounds__(256) void k_conv12(
    const float* __restrict__ a,  const float* __restrict__ w1, const float* __restrict__ w2,
    const float* __restrict__ b1, const float* __restrict__ g1, const float* __restrict__ be1,
    const float* __restrict__ m1, const float* __restrict__ v1,
    const float* __restrict__ b2, const float* __restrict__ g2, const float* __restrict__ be2,
    const float* __restrict__ m2, const float* __restrict__ v2,
    u16* __restrict__ y1, u16* __restrict__ y2)
{
  __shared__ __align__(16) u16 aT[32*512];   // 32KB: c-chunk x 512 px (bf16)
  __shared__ __align__(16) u16 wT[2*16*256]; // 16KB: [conv][oc][c] (bf16)
  const int tid = threadIdx.x;
  const int wv = tid>>6, ln = tid&63;
  const int px0 = blockIdx.x*512;
  const int oc0 = blockIdx.y*16;
  const int b   = blockIdx.z;

  { // stage weight tiles (rows oc0..oc0+15 contiguous): 4096 f32 each
    const float* s1 = w1 + oc0*256;
    const float* s2 = w2 + oc0*256;
    #pragma unroll
    for (int it=0; it<4; ++it){
      int idx = (it*256+tid)*4;
      float4 f1 = *(const float4*)&s1[idx];
      float4 f2 = *(const float4*)&s2[idx];
      *(uint2*)&wT[idx]      = make_uint2(pack2(f1.x,f1.y), pack2(f1.z,f1.w));
      *(uint2*)&wT[4096+idx] = make_uint2(pack2(f2.x,f2.y), pack2(f2.z,f2.w));
    }
  }
  float acc[2][4][8];
  #pragma unroll
  for(int cv=0;cv<2;cv++){
    #pragma unroll
    for(int u=0;u<4;u++){
      #pragma unroll
      for(int p=0;p<8;p++) acc[cv][u][p]=0.f;
    }
  }

  const float* abase = a + b*1048576 + px0;
  for (int kc=0; kc<8; ++kc){
    __syncthreads();
    #pragma unroll
    for (int it=0; it<16; ++it){
      int idx = (it*256+tid)*4;        // 0..16380, float index in chunk
      int c = idx>>9, px = idx&511;
      float4 f = *(const float4*)&abase[(kc*32+c)*4096 + px];
      *(uint2*)&aT[idx] = make_uint2(pack2(f.x,f.y), pack2(f.z,f.w));
    }
    __syncthreads();
    #pragma unroll
    for (int cc=0; cc<32; cc+=2){
      u32 av[2][4], wwv[2][4];
      #pragma unroll
      for(int k=0;k<4;k++){
        av[0][k] = *(const u32*)&aT[ cc   *512 + 2*ln + 128*k];
        av[1][k] = *(const u32*)&aT[(cc+1)*512 + 2*ln + 128*k];
      }
      const int cgl = kc*32+cc;
      #pragma unroll
      for(int u=0;u<4;u++){
        wwv[0][u] = *(const u32*)&wT[       (wv*4+u)*256 + cgl];
        wwv[1][u] = *(const u32*)&wT[4096 + (wv*4+u)*256 + cgl];
      }
      #pragma unroll
      for(int cv=0; cv<2; ++cv){
        #pragma unroll
        for(int u=0;u<4;u++){
          float w0 = bflo(wwv[cv][u]), w1v = bfhi(wwv[cv][u]);
          #pragma unroll
          for(int k=0;k<4;k++){
            acc[cv][u][2*k]   += bflo(av[0][k])*w0 + bflo(av[1][k])*w1v;
            acc[cv][u][2*k+1] += bfhi(av[0][k])*w0 + bfhi(av[1][k])*w1v;
          }
        }
      }
    }
  }
  #pragma unroll
  for(int cv=0; cv<2; ++cv){
    const float *bb = cv? b2:b1, *gg = cv? g2:g1, *bt = cv? be2:be1, *mm = cv? m2:m1, *vv = cv? v2:v1;
    u16* y = cv? y2 : y1;
    #pragma unroll
    for(int u=0;u<4;u++){
      int oc = oc0 + wv*4 + u;
      float bias = bb[oc];
      float sc = gg[oc] / sqrtf(vv[oc] + 1e-5f);
      float sh = bt[oc] - mm[oc]*sc;
      u16* yb = y + b*524288 + oc*4096 + px0;
      #pragma unroll
      for(int k=0;k<4;k++){
        float r0 = fmaxf((acc[cv][u][2*k]  +bias)*sc + sh, 0.f);
        float r1 = fmaxf((acc[cv][u][2*k+1]+bias)*sc + sh, 0.f);
        *(u32*)&yb[2*ln + 128*k] = pack2(r0, r1);
      }
    }
  }
}

// ---------------- K2: maxpool 3x3 s2 p1 : y2[8,128,64,64] bf16 -> p[8,128,32,32] bf16 ----------
__global__ __launch_bounds__(256) void k_pool(const u16* __restrict__ y2, u16* __restrict__ p){
  int idx = blockIdx.x*256 + threadIdx.x;        // < 1,048,576
  int b = idx>>17, rem = idx & 131071;
  int c = rem>>10, op = rem&1023;
  int oh = op>>5, ow = op&31;
  const u16* base = y2 + b*524288 + c*4096;
  float mx = -1e30f;
  #pragma unroll
  for(int dh=-1; dh<=1; ++dh){
    int ih = 2*oh+dh;
    if ((unsigned)ih < 64u){
      #pragma unroll
      for(int dw=-1; dw<=1; ++dw){
        int iw = 2*ow+dw;
        if((unsigned)iw<64u) mx = fmaxf(mx, bf2f(base[ih*64+iw]));
      }
    }
  }
  p[idx] = f2bf(mx);
}

// ---------------- K3: attention: softmax(x1 @ x2) @ x3 ; O written IN-PLACE over y1 ------------
// 16 rows/block; wave rg owns rows {R0+rg*4..+3}; lane ln owns cols {ln+64m, m=0..15}.
__global__ __launch_bounds__(256) void k_attn(u16* __restrict__ y1,
                                              const u16* __restrict__ pbuf)
{
  __shared__ __align__(16) u16 qT[16*128];   // 4KB
  __shared__ __align__(16) u16 kT[16*1024];  // 32KB, reused as P tile
  const int tid=threadIdx.x, rg=tid>>6, ln=tid&63;
  const int R0 = blockIdx.x*16;
  const int b  = blockIdx.y;
  u16* Q = y1  + b*524288;
  const u16* P = pbuf + b*131072;

  { int e = tid*8; *(uint4*)&qT[e] = *(const uint4*)&Q[R0*128 + e]; }

  float S[4][16];
  #pragma unroll
  for(int r=0;r<4;r++){
    #pragma unroll
    for(int m=0;m<16;m++) S[r][m]=0.f;
  }

  for(int jc=0;jc<8;jc++){
    __syncthreads();
    #pragma unroll
    for(int it=0; it<8; ++it){
      int e = (it*256+tid)*8;
      *(uint4*)&kT[e] = *(const uint4*)&P[jc*16384 + e];
    }
    __syncthreads();
    #pragma unroll
    for(int jj=0;jj<16;jj+=2){
      u32 qp[4];
      #pragma unroll
      for(int r=0;r<4;r++) qp[r] = *(const u32*)&qT[(rg*4+r)*128 + jc*16 + jj];
      #pragma unroll
      for(int m=0;m<16;m++){
        float k0 = bf2f(kT[ jj   *1024 + ln + 64*m]);
        float k1 = bf2f(kT[(jj+1)*1024 + ln + 64*m]);
        #pragma unroll
        for(int r=0;r<4;r++)
          S[r][m] += bflo(qp[r])*k0 + bfhi(qp[r])*k1;
      }
    }
  }
  __syncthreads();            // all S done; kT space becomes P tile
  u16* pT = kT;
  #pragma unroll
  for(int r=0;r<4;r++){
    float mx = S[r][0];
    #pragma unroll
    for(int m=1;m<16;m++) mx = fmaxf(mx, S[r][m]);
    #pragma unroll
    for(int d=1; d<64; d<<=1) mx = fmaxf(mx, __shfl_xor(mx, d, 64));
    float sum = 0.f;
    #pragma unroll
    for(int m=0;m<16;m++){ float t = __expf(S[r][m]-mx); S[r][m]=t; sum += t; }
    #pragma unroll
    for(int d=1; d<64; d<<=1) sum += __shfl_xor(sum, d, 64);
    float inv = 1.0f/sum;
    #pragma unroll
    for(int m=0;m<16;m++) pT[(rg*4+r)*1024 + ln + 64*m] = f2bf(S[r][m]*inv);
  }
  __syncthreads();

  float o[4][2];
  #pragma unroll
  for(int r=0;r<4;r++){ o[r][0]=0.f; o[r][1]=0.f; }
  const u16* V = pbuf + b*131072;
  #pragma unroll 4
  for(int k=0;k<1024;k+=2){
    u32 v0 = *(const u32*)&V[ k   *128 + 2*ln];
    u32 v1 = *(const u32*)&V[(k+1)*128 + 2*ln];
    u32 pp[4];
    #pragma unroll
    for(int r=0;r<4;r++) pp[r] = *(const u32*)&pT[(rg*4+r)*1024 + k];
    #pragma unroll
    for(int r=0;r<4;r++){
      float p0=bflo(pp[r]), p1=bfhi(pp[r]);
      o[r][0] += p0*bflo(v0) + p1*bflo(v1);
      o[r][1] += p0*bfhi(v0) + p1*bfhi(v1);
    }
  }
  // write O rows R0..R0+15 over y1's same rows (only this block ever reads them; Q already in LDS)
  u16* ob = Q + R0*128;
  #pragma unroll
  for(int r=0;r<4;r++)
    *(u32*)&ob[(rg*4+r)*128 + 2*ln] = pack2(o[r][0], o[r][1]);
}

// ---------------- K4: conv3 + bias + BN + ReLU + residual; bf16 o4 in, f32 out ----------------
__global__ __launch_bounds__(256) void k_conv3(
    const u16* __restrict__ o4, const float* __restrict__ w3,
    const float* __restrict__ b3, const float* __restrict__ g3, const float* __restrict__ be3,
    const float* __restrict__ m3, const float* __restrict__ v3,
    const float* __restrict__ a,  float* __restrict__ out)
{
  __shared__ __align__(16) u16 aT[32*512];  // 32KB
  __shared__ __align__(16) u16 wT[16*128];  // 4KB
  const int tid=threadIdx.x, wv=tid>>6, ln=tid&63;
  const int px0 = blockIdx.x*512;
  const int oc0 = blockIdx.y*16;
  const int b   = blockIdx.z;
  { // stage w3 tile: 2048 f32
    const float* s = w3 + oc0*128;
    #pragma unroll
    for(int it=0; it<2; ++it){
      int idx = (it*256+tid)*4;
      float4 f = *(const float4*)&s[idx];
      *(uint2*)&wT[idx] = make_uint2(pack2(f.x,f.y), pack2(f.z,f.w));
    }
  }
  float acc[4][8];
  #pragma unroll
  for(int u=0;u<4;u++){
    #pragma unroll
    for(int p=0;p<8;p++) acc[u][p]=0.f;
  }
  const u16* ib = o4 + b*524288 + px0;
  for(int kc=0;kc<4;kc++){
    __syncthreads();
    #pragma unroll
    for(int it=0;it<8;++it){
      int e=(it*256+tid)*8;
      int c=e>>9, px=e&511;
      *(uint4*)&aT[e] = *(const uint4*)&ib[(kc*32+c)*4096 + px];
    }
    __syncthreads();
    #pragma unroll
    for(int cc=0;cc<32;cc+=2){
      u32 av[2][4], ww[4];
      #pragma unroll
      for(int k=0;k<4;k++){
        av[0][k]=*(const u32*)&aT[ cc   *512+2*ln+128*k];
        av[1][k]=*(const u32*)&aT[(cc+1)*512+2*ln+128*k];
      }
      const int cgl=kc*32+cc;
      #pragma unroll
      for(int u=0;u<4;u++) ww[u]=*(const u32*)&wT[(wv*4+u)*128+cgl];
      #pragma unroll
      for(int u=0;u<4;u++){
        float w0=bflo(ww[u]), w1v=bfhi(ww[u]);
        #pragma unroll
        for(int k=0;k<4;k++){
          acc[u][2*k]   += bflo(av[0][k])*w0 + bflo(av[1][k])*w1v;
          acc[u][2*k+1] += bfhi(av[0][k])*w0 + bfhi(av[1][k])*w1v;
        }
      }
    }
  }
  #pragma unroll
  for(int u=0;u<4;u++){
    int oc=oc0+wv*4+u;
    float bias=b3[oc];
    float sc=g3[oc]/sqrtf(v3[oc]+1e-5f);
    float sh=be3[oc]-m3[oc]*sc;
    const float* ares = a + b*1048576 + oc*4096 + px0;
    float* ob = out + b*1048576 + oc*4096 + px0;
    #pragma unroll
    for(int k=0;k<4;k++){
      float2 ap = *(const float2*)&ares[2*ln+128*k];
      float r0 = fmaxf((acc[u][2*k]  +bias)*sc+sh, 0.f) + ap.x;
      float r1 = fmaxf((acc[u][2*k+1]+bias)*sc+sh, 0.f) + ap.y;
      *(float2*)&ob[2*ln+128*k] = make_float2(r0,r1);
    }
  }
}

extern "C" void kernel_launch(void* const* d_in, const int* in_sizes, int n_in,
                              void* d_out, int out_size, void* d_ws, size_t ws_size,
                              hipStream_t stream)
{
  const float* a   = (const float*)d_in[0];
  const float* w1  = (const float*)d_in[1];
  const float* b1  = (const float*)d_in[2];
  const float* g1  = (const float*)d_in[3];
  const float* be1 = (const float*)d_in[4];
  const float* m1  = (const float*)d_in[5];
  const float* v1  = (const float*)d_in[6];
  const float* w2  = (const float*)d_in[7];
  const float* b2  = (const float*)d_in[8];
  const float* g2  = (const float*)d_in[9];
  const float* be2 = (const float*)d_in[10];
  const float* m2  = (const float*)d_in[11];
  const float* v2  = (const float*)d_in[12];
  const float* w3  = (const float*)d_in[13];
  const float* b3  = (const float*)d_in[14];
  const float* g3  = (const float*)d_in[15];
  const float* be3 = (const float*)d_in[16];
  const float* m3  = (const float*)d_in[17];
  const float* v3  = (const float*)d_in[18];
  float* out = (float*)d_out;

  u16* y1 = (u16*)d_ws;                 // 4,194,304 bf16 elems; becomes o4 in-place
  u16* p  = y1 + 4194304;               // 1,048,576 bf16 elems   (ws use: 10.5 MB total)
  u16* y2 = (u16*)d_out;                // scratch inside d_out (16.8MB of 33.5MB); dead before conv3

  k_conv12<<<dim3(8,8,8),   256, 0, stream>>>(a,w1,w2,b1,g1,be1,m1,v1,b2,g2,be2,m2,v2,y1,y2);
  k_pool  <<<dim3(4096),    256, 0, stream>>>(y2, p);
  k_attn  <<<dim3(256,8),   256, 0, stream>>>(y1, p);
  k_conv3 <<<dim3(8,16,8),  256, 0, stream>>>(y1,w3,b3,g3,be3,m3,v3,a,out);
}

// Round 5
// 806.519 us; speedup vs baseline: 1.9507x; 1.9507x over previous
//
#include <hip/hip_runtime.h>
#include <hip/hip_bf16.h>

// Non-local attention block, B=8 C=256 C2=128 H=W=64 (HW=4096), pooled 32x32 (1024).
// Global tensors FLOAT32; intermediates bf16.
//
// Flat-reshape identities:
//   Q  = y1 viewed [4096][128] row-major (rows contiguous)
//   S  = Q @ X2, X2[j][k] = p_flat[j*1024+k]       -> B^T = pT[pos][chan]   (pool writes it)
//   O  = P @ X3, X3[k][j] = p_flat[k*128+j]        -> B^T = x3T[chan][kv]   (pool writes it)
//   O rows write straight back over y1 (in-place); conv3 consumes y1.
//
// Buffers: y1 bf16 in ws (4,194,304 u16). In d_out (16,777,216 u16 capacity):
//   y2 @0 (4,194,304), pT @4,194,304 (1,048,576), x3T @5,242,880 (1,048,576) — all dead before conv3 writes f32 out.

typedef unsigned short u16;
typedef unsigned int u32;
typedef short  bf16x8 __attribute__((ext_vector_type(8)));   // 8 bf16 (4 VGPRs)
typedef float  f32x4  __attribute__((ext_vector_type(4)));

#define DEV static __device__ __forceinline__

DEV float bf2f(u16 v){ return __uint_as_float(((u32)v)<<16); }
DEV float bflo(u32 p){ return __uint_as_float(p<<16); }
DEV float bfhi(u32 p){ return __uint_as_float(p & 0xFFFF0000u); }
DEV u16 f2bf(float f){
  u32 x = __float_as_uint(f);
  x += 0x7FFFu + ((x>>16)&1u);   // RNE
  return (u16)(x>>16);
}
DEV u32 pack2(float a, float b){ return ((u32)f2bf(a)) | (((u32)f2bf(b))<<16); }

// ---------------- K1: fused conv1 + conv2 (1x1 + bias + BN + ReLU), f32 in, bf16 out ----------
__global__ __launch_bounds__(256) void k_conv12(
    const float* __restrict__ a,  const float* __restrict__ w1, const float* __restrict__ w2,
    const float* __restrict__ b1, const float* __restrict__ g1, const float* __restrict__ be1,
    const float* __restrict__ m1, const float* __restrict__ v1,
    const float* __restrict__ b2, const float* __restrict__ g2, const float* __restrict__ be2,
    const float* __restrict__ m2, const float* __restrict__ v2,
    u16* __restrict__ y1, u16* __restrict__ y2)
{
  __shared__ __align__(16) u16 aT[32*512];
  __shared__ __align__(16) u16 wT[2*16*256];
  const int tid = threadIdx.x;
  const int wv = tid>>6, ln = tid&63;
  const int px0 = blockIdx.x*512;
  const int oc0 = blockIdx.y*16;
  const int b   = blockIdx.z;

  {
    const float* s1 = w1 + oc0*256;
    const float* s2 = w2 + oc0*256;
    #pragma unroll
    for (int it=0; it<4; ++it){
      int idx = (it*256+tid)*4;
      float4 f1 = *(const float4*)&s1[idx];
      float4 f2 = *(const float4*)&s2[idx];
      *(uint2*)&wT[idx]      = make_uint2(pack2(f1.x,f1.y), pack2(f1.z,f1.w));
      *(uint2*)&wT[4096+idx] = make_uint2(pack2(f2.x,f2.y), pack2(f2.z,f2.w));
    }
  }
  float acc[2][4][8];
  #pragma unroll
  for(int cv=0;cv<2;cv++){
    #pragma unroll
    for(int u=0;u<4;u++){
      #pragma unroll
      for(int p=0;p<8;p++) acc[cv][u][p]=0.f;
    }
  }

  const float* abase = a + b*1048576 + px0;
  for (int kc=0; kc<8; ++kc){
    __syncthreads();
    #pragma unroll
    for (int it=0; it<16; ++it){
      int idx = (it*256+tid)*4;
      int c = idx>>9, px = idx&511;
      float4 f = *(const float4*)&abase[(kc*32+c)*4096 + px];
      *(uint2*)&aT[idx] = make_uint2(pack2(f.x,f.y), pack2(f.z,f.w));
    }
    __syncthreads();
    #pragma unroll
    for (int cc=0; cc<32; cc+=2){
      u32 av[2][4], wwv[2][4];
      #pragma unroll
      for(int k=0;k<4;k++){
        av[0][k] = *(const u32*)&aT[ cc   *512 + 2*ln + 128*k];
        av[1][k] = *(const u32*)&aT[(cc+1)*512 + 2*ln + 128*k];
      }
      const int cgl = kc*32+cc;
      #pragma unroll
      for(int u=0;u<4;u++){
        wwv[0][u] = *(const u32*)&wT[       (wv*4+u)*256 + cgl];
        wwv[1][u] = *(const u32*)&wT[4096 + (wv*4+u)*256 + cgl];
      }
      #pragma unroll
      for(int cv=0; cv<2; ++cv){
        #pragma unroll
        for(int u=0;u<4;u++){
          float w0 = bflo(wwv[cv][u]), w1v = bfhi(wwv[cv][u]);
          #pragma unroll
          for(int k=0;k<4;k++){
            acc[cv][u][2*k]   += bflo(av[0][k])*w0 + bflo(av[1][k])*w1v;
            acc[cv][u][2*k+1] += bfhi(av[0][k])*w0 + bfhi(av[1][k])*w1v;
          }
        }
      }
    }
  }
  #pragma unroll
  for(int cv=0; cv<2; ++cv){
    const float *bb = cv? b2:b1, *gg = cv? g2:g1, *bt = cv? be2:be1, *mm = cv? m2:m1, *vv = cv? v2:v1;
    u16* y = cv? y2 : y1;
    #pragma unroll
    for(int u=0;u<4;u++){
      int oc = oc0 + wv*4 + u;
      float bias = bb[oc];
      float sc = gg[oc] / sqrtf(vv[oc] + 1e-5f);
      float sh = bt[oc] - mm[oc]*sc;
      u16* yb = y + b*524288 + oc*4096 + px0;
      #pragma unroll
      for(int k=0;k<4;k++){
        float r0 = fmaxf((acc[cv][u][2*k]  +bias)*sc + sh, 0.f);
        float r1 = fmaxf((acc[cv][u][2*k+1]+bias)*sc + sh, 0.f);
        *(u32*)&yb[2*ln + 128*k] = pack2(r0, r1);
      }
    }
  }
}

// ---------------- K2: maxpool 3x3 s2 p1 -> writes pT[pos][chan] and x3T[chan-interleave] --------
__global__ __launch_bounds__(256) void k_pool(const u16* __restrict__ y2,
                                              u16* __restrict__ pTg, u16* __restrict__ x3Tg){
  int idx = blockIdx.x*256 + threadIdx.x;        // < 1,048,576
  int b = idx>>17, rem = idx & 131071;
  int c = rem>>10, pos = rem&1023;
  int oh = pos>>5, ow = pos&31;
  const u16* base = y2 + b*524288 + c*4096;
  float mx = -1e30f;
  #pragma unroll
  for(int dh=-1; dh<=1; ++dh){
    int ih = 2*oh+dh;
    if ((unsigned)ih < 64u){
      #pragma unroll
      for(int dw=-1; dw<=1; ++dw){
        int iw = 2*ow+dw;
        if((unsigned)iw<64u) mx = fmaxf(mx, bf2f(base[ih*64+iw]));
      }
    }
  }
  u16 v = f2bf(mx);
  pTg[b*131072 + pos*128 + c] = v;               // pT[pos][chan]
  int f = c*1024 + pos;                          // flat idx in original p
  x3Tg[b*131072 + (f&127)*1024 + (f>>7)] = v;    // x3T[j][k], X3[k][j]=p_flat[k*128+j]
}

// ---------------- K3: MFMA flash attention; O over y1 in-place -------------------------------
// Block: 64 q-rows, 4 waves x 16 rows. 16 kv-chunks of 64. S^T = mfma(K_frag, Q_frag).
__global__ __launch_bounds__(256) void k_attn_mfma(u16* __restrict__ y1,
    const u16* __restrict__ pTg, const u16* __restrict__ x3Tg)
{
  __shared__ __align__(16) u16 qT[64*128];   // 16KB, swz: byte=row*256+((c16^(row&15))<<4)
  __shared__ __align__(16) u16 kT[64*128];   // 16KB, same swizzle
  __shared__ __align__(16) u16 vT[128*64];   // 16KB, swz: byte=row*128+((c16^(row&7))<<4)
  __shared__ __align__(16) u16 pS[4][1024];  // 8KB,  swz: byte=q*128+((kv4^q)<<3)

  const int tid = threadIdx.x, w = tid>>6, l = tid&63;
  const int g = l>>4, q = l&15;
  const int b = blockIdx.y;
  const int R0 = blockIdx.x*64;
  u16* y1b = y1 + b*524288;
  const u16* pTb = pTg + b*131072;
  const u16* vTb = x3Tg + b*131072;

  // stage Q tile (rows R0..R0+63), swizzled
  #pragma unroll
  for (int it=0; it<4; ++it){
    int idx = it*256 + tid;                  // 0..1023 16B-chunks
    int row = idx>>4, c16 = idx&15;
    uint4 d = *(const uint4*)(y1b + (R0+row)*128 + c16*8);
    *(uint4*)((char*)qT + row*256 + ((c16 ^ (row&15))<<4)) = d;
  }
  __syncthreads();

  // preload Q B-frags (wave's 16 rows; row&15 == q)
  bf16x8 qf[4];
  #pragma unroll
  for (int kk=0; kk<4; ++kk)
    qf[kk] = *(const bf16x8*)((char*)qT + (w*16+q)*256 + (((kk*4+g) ^ q)<<4));

  f32x4 O[8];
  #pragma unroll
  for (int t=0;t<8;t++) O[t] = (f32x4){0.f,0.f,0.f,0.f};
  float m = -3.0e38f, s = 0.f;

  for (int ch=0; ch<16; ++ch){
    const int kv0 = ch*64;
    // issue chunk loads before barrier (overlap other waves' compute)
    uint4 kreg[4], vreg[4];
    #pragma unroll
    for (int it=0; it<4; ++it){
      int idx = it*256 + tid;
      kreg[it] = *(const uint4*)(pTb + (kv0 + (idx>>4))*128 + (idx&15)*8);
      vreg[it] = *(const uint4*)(vTb + (idx>>3)*1024 + kv0 + (idx&7)*8);
    }
    __syncthreads();   // everyone done with prev kT/vT
    #pragma unroll
    for (int it=0; it<4; ++it){
      int idx = it*256 + tid;
      int row = idx>>4, c16 = idx&15;
      *(uint4*)((char*)kT + row*256 + ((c16 ^ (row&15))<<4)) = kreg[it];
      int vr = idx>>3, vc = idx&7;
      *(uint4*)((char*)vT + vr*128 + ((vc ^ (vr&7))<<4)) = vreg[it];
    }
    __syncthreads();

    // S^T: 4 kv-tiles x K=128; D[m=kv][n=q]: lane holds kv = n*16+g*4+e for its q
    f32x4 st[4];
    #pragma unroll
    for (int n=0;n<4;n++) st[n] = (f32x4){0.f,0.f,0.f,0.f};
    #pragma unroll
    for (int kk=0; kk<4; ++kk){
      #pragma unroll
      for (int n=0;n<4;n++){
        bf16x8 kf = *(const bf16x8*)((char*)kT + (n*16+q)*256 + (((kk*4+g) ^ q)<<4));
        st[n] = __builtin_amdgcn_mfma_f32_16x16x32_bf16(kf, qf[kk], st[n], 0,0,0);
      }
    }

    // online softmax for lane's q-row (row spread over lanes q, q+16, q+32, q+48)
    float cmax = st[0][0];
    #pragma unroll
    for(int n=0;n<4;n++){
      #pragma unroll
      for(int e=0;e<4;e++) cmax = fmaxf(cmax, st[n][e]);
    }
    cmax = fmaxf(cmax, __shfl_xor(cmax,16,64));
    cmax = fmaxf(cmax, __shfl_xor(cmax,32,64));
    float mnew = fmaxf(m, cmax);
    float corr = __expf(m - mnew);
    m = mnew;
    float psum = 0.f;
    #pragma unroll
    for(int n=0;n<4;n++){
      #pragma unroll
      for(int e=0;e<4;e++){ float t_ = __expf(st[n][e]-m); st[n][e]=t_; psum += t_; }
    }
    psum += __shfl_xor(psum,16,64);
    psum += __shfl_xor(psum,32,64);
    s = s*corr + psum;

    // rescale O (O rows q' = g*4+e; corr lives in lane q')
    float cO[4];
    #pragma unroll
    for(int e=0;e<4;e++) cO[e] = __shfl(corr, g*4+e, 64);
    #pragma unroll
    for(int t=0;t<8;t++){
      #pragma unroll
      for(int e=0;e<4;e++) O[t][e] *= cO[e];
    }

    // P -> per-wave LDS (row q, kv consecutive), swizzled 8B units
    u16* pSw = pS[w];
    #pragma unroll
    for(int n=0;n<4;n++){
      u32 lo = pack2(st[n][0], st[n][1]);
      u32 hi = pack2(st[n][2], st[n][3]);
      *(uint2*)((char*)pSw + q*128 + (((n*4+g) ^ q)<<3)) = make_uint2(lo,hi);
    }

    // PV: O[q][chan] += P[q][kv] * X3[kv][chan]
    #pragma unroll
    for(int kk2=0; kk2<2; ++kk2){
      int kv4a = kk2*8 + g*2;
      uint2 A0 = *(const uint2*)((char*)pSw + q*128 + (((kv4a  ) ^ q)<<3));
      uint2 A1 = *(const uint2*)((char*)pSw + q*128 + (((kv4a+1) ^ q)<<3));
      uint4 pa4 = make_uint4(A0.x, A0.y, A1.x, A1.y);
      bf16x8 pf = *(bf16x8*)&pa4;
      #pragma unroll
      for(int t=0;t<8;t++){
        bf16x8 vf = *(const bf16x8*)((char*)vT + (t*16+q)*128 + (((kk2*4+g) ^ (q&7))<<4));
        O[t] = __builtin_amdgcn_mfma_f32_16x16x32_bf16(pf, vf, O[t], 0,0,0);
      }
    }
  }

  // epilogue: divide by s, write O rows back over y1
  float si[4];
  #pragma unroll
  for(int e=0;e<4;e++) si[e] = 1.0f / __shfl(s, g*4+e, 64);
  #pragma unroll
  for(int t=0;t<8;t++){
    #pragma unroll
    for(int e=0;e<4;e++){
      int grow = R0 + w*16 + g*4 + e;
      y1b[grow*128 + t*16 + q] = f2bf(O[t][e]*si[e]);
    }
  }
}

// ---------------- K4: conv3 + bias + BN + ReLU + residual; bf16 o4 in, f32 out ----------------
__global__ __launch_bounds__(256) void k_conv3(
    const u16* __restrict__ o4, const float* __restrict__ w3,
    const float* __restrict__ b3, const float* __restrict__ g3, const float* __restrict__ be3,
    const float* __restrict__ m3, const float* __restrict__ v3,
    const float* __restrict__ a,  float* __restrict__ out)
{
  __shared__ __align__(16) u16 aT[32*512];
  __shared__ __align__(16) u16 wT[16*128];
  const int tid=threadIdx.x, wv=tid>>6, ln=tid&63;
  const int px0 = blockIdx.x*512;
  const int oc0 = blockIdx.y*16;
  const int b   = blockIdx.z;
  {
    const float* s = w3 + oc0*128;
    #pragma unroll
    for(int it=0; it<2; ++it){
      int idx = (it*256+tid)*4;
      float4 f = *(const float4*)&s[idx];
      *(uint2*)&wT[idx] = make_uint2(pack2(f.x,f.y), pack2(f.z,f.w));
    }
  }
  float acc[4][8];
  #pragma unroll
  for(int u=0;u<4;u++){
    #pragma unroll
    for(int p=0;p<8;p++) acc[u][p]=0.f;
  }
  const u16* ib = o4 + b*524288 + px0;
  for(int kc=0;kc<4;kc++){
    __syncthreads();
    #pragma unroll
    for(int it=0;it<8;++it){
      int e=(it*256+tid)*8;
      int c=e>>9, px=e&511;
      *(uint4*)&aT[e] = *(const uint4*)&ib[(kc*32+c)*4096 + px];
    }
    __syncthreads();
    #pragma unroll
    for(int cc=0;cc<32;cc+=2){
      u32 av[2][4], ww[4];
      #pragma unroll
      for(int k=0;k<4;k++){
        av[0][k]=*(const u32*)&aT[ cc   *512+2*ln+128*k];
        av[1][k]=*(const u32*)&aT[(cc+1)*512+2*ln+128*k];
      }
      const int cgl=kc*32+cc;
      #pragma unroll
      for(int u=0;u<4;u++) ww[u]=*(const u32*)&wT[(wv*4+u)*128+cgl];
      #pragma unroll
      for(int u=0;u<4;u++){
        float w0=bflo(ww[u]), w1v=bfhi(ww[u]);
        #pragma unroll
        for(int k=0;k<4;k++){
          acc[u][2*k]   += bflo(av[0][k])*w0 + bflo(av[1][k])*w1v;
          acc[u][2*k+1] += bfhi(av[0][k])*w0 + bfhi(av[1][k])*w1v;
        }
      }
    }
  }
  #pragma unroll
  for(int u=0;u<4;u++){
    int oc=oc0+wv*4+u;
    float bias=b3[oc];
    float sc=g3[oc]/sqrtf(v3[oc]+1e-5f);
    float sh=be3[oc]-m3[oc]*sc;
    const float* ares = a + b*1048576 + oc*4096 + px0;
    float* ob = out + b*1048576 + oc*4096 + px0;
    #pragma unroll
    for(int k=0;k<4;k++){
      float2 ap = *(const float2*)&ares[2*ln+128*k];
      float r0 = fmaxf((acc[u][2*k]  +bias)*sc+sh, 0.f) + ap.x;
      float r1 = fmaxf((acc[u][2*k+1]+bias)*sc+sh, 0.f) + ap.y;
      *(float2*)&ob[2*ln+128*k] = make_float2(r0,r1);
    }
  }
}

extern "C" void kernel_launch(void* const* d_in, const int* in_sizes, int n_in,
                              void* d_out, int out_size, void* d_ws, size_t ws_size,
                              hipStream_t stream)
{
  const float* a   = (const float*)d_in[0];
  const float* w1  = (const float*)d_in[1];
  const float* b1  = (const float*)d_in[2];
  const float* g1  = (const float*)d_in[3];
  const float* be1 = (const float*)d_in[4];
  const float* m1  = (const float*)d_in[5];
  const float* v1  = (const float*)d_in[6];
  const float* w2  = (const float*)d_in[7];
  const float* b2  = (const float*)d_in[8];
  const float* g2  = (const float*)d_in[9];
  const float* be2 = (const float*)d_in[10];
  const float* m2  = (const float*)d_in[11];
  const float* v2  = (const float*)d_in[12];
  const float* w3  = (const float*)d_in[13];
  const float* b3  = (const float*)d_in[14];
  const float* g3  = (const float*)d_in[15];
  const float* be3 = (const float*)d_in[16];
  const float* m3  = (const float*)d_in[17];
  const float* v3  = (const float*)d_in[18];
  float* out = (float*)d_out;

  u16* y1   = (u16*)d_ws;               // 4,194,304 u16 (8MB); O in-place
  u16* d16  = (u16*)d_out;
  u16* y2   = d16;                      // 4,194,304 u16 scratch in d_out
  u16* pT   = d16 + 4194304;            // 1,048,576 u16
  u16* x3T  = d16 + 5242880;            // 1,048,576 u16 (all dead before conv3 writes)

  k_conv12   <<<dim3(8,8,8),  256, 0, stream>>>(a,w1,w2,b1,g1,be1,m1,v1,b2,g2,be2,m2,v2,y1,y2);
  k_pool     <<<dim3(4096),   256, 0, stream>>>(y2, pT, x3T);
  k_attn_mfma<<<dim3(64,8),   256, 0, stream>>>(y1, pT, x3T);
  k_conv3    <<<dim3(8,16,8), 256, 0, stream>>>(y1,w3,b3,g3,be3,m3,v3,a,out);
}

// Round 8
// 249.292 us; speedup vs baseline: 6.3109x; 3.2352x over previous
//
#include <hip/hip_runtime.h>
#include <hip/hip_bf16.h>

// Non-local attention block, B=8 C=256 C2=128 H=W=64 (HW=4096), pooled 32x32 (1024).
// Round 8: fixes round-6/7 semantic bug — y1 MUST be NCHW [c2][hw] so the attention's
// [4096][128] row view equals the reference's RAW reshape (row i = 128 consecutive hw
// of channel i>>5). Reverted conv1 epilogue to NCHW stores.
// Pipeline:
//   T1:      a (f32 NCHW) -> aTg bf16 [b][px][c]          (LDS transpose)
//   conv12m: MFMA GEMM -> y1 bf16 NCHW [b][c2][hw], y2 bf16 NCHW [b][c2][hw]
//   pool:    y2 -> pT [b][pos][chan], x3T [b][j][k]  (raw-view transposes for attention)
//   attn:    flash MFMA on raw views; O rows written flat over y1 (== o4 NCHW flat)
//   T2:      y1 (o4 NCHW [c2][hw]) -> x4T bf16 [b][hw][c2]
//   conv3m:  MFMA GEMM + BN + ReLU + residual -> out f32 NCHW
//
// d_out scratch (u16 idx, cap 16,777,216): aTg @0 (8.4M, dead after conv12; pool then
//   reuses @0 for pT (1M) and @1M for x3T (1M)), y2 @8,388,608 (4.2M), y1 @12,582,912 (4.2M).
// ws: x4T @0 (4.2M u16 = 8 MB).

typedef unsigned short u16;
typedef unsigned int u32;
typedef short  bf16x8 __attribute__((ext_vector_type(8)));
typedef float  f32x4  __attribute__((ext_vector_type(4)));

#define DEV static __device__ __forceinline__

DEV float bf2f(u16 v){ return __uint_as_float(((u32)v)<<16); }
DEV float bflo(u32 p){ return __uint_as_float(p<<16); }
DEV float bfhi(u32 p){ return __uint_as_float(p & 0xFFFF0000u); }
DEV u16 f2bf(float f){
  u32 x = __float_as_uint(f);
  x += 0x7FFFu + ((x>>16)&1u);   // RNE
  return (u16)(x>>16);
}
DEV u32 pack2(float a, float b){ return ((u32)f2bf(a)) | (((u32)f2bf(b))<<16); }

// ---------------- T1: a f32 NCHW [256][4096] -> aTg bf16 [4096 px][256 c] ----------------
__global__ __launch_bounds__(256) void k_t1(const float* __restrict__ a, u16* __restrict__ aTg){
  __shared__ u16 L[64*72];                      // 64 hw x 64 c tile, row pad 72
  const int t = threadIdx.x;
  const int hw0 = blockIdx.x*64, c0 = blockIdx.y*64, b = blockIdx.z;
  const float* ab = a + b*1048576;
  #pragma unroll
  for(int it=0; it<4; ++it){
    int c = it*16 + (t>>4);
    int hw = (t&15)*4;
    float4 f = *(const float4*)&ab[(c0+c)*4096 + hw0 + hw];
    L[(hw+0)*72 + c] = f2bf(f.x);
    L[(hw+1)*72 + c] = f2bf(f.y);
    L[(hw+2)*72 + c] = f2bf(f.z);
    L[(hw+3)*72 + c] = f2bf(f.w);
  }
  __syncthreads();
  u16* ob = aTg + b*1048576;
  #pragma unroll
  for(int it=0; it<2; ++it){
    int g2 = it*256 + t;
    int hw = g2>>3, k = g2&7;
    *(uint4*)&ob[(hw0+hw)*256 + c0 + k*8] = *(const uint4*)&L[hw*72 + k*8];
  }
}

// ---------------- T2: y1 (o4 NCHW [128 c2][4096 hw]) -> x4T [hw][c2] --------------------
__global__ __launch_bounds__(256) void k_t2(const u16* __restrict__ y1, u16* __restrict__ x4T){
  __shared__ u16 L[64*72];
  const int t = threadIdx.x;
  const int hw0 = blockIdx.x*64, c20 = blockIdx.y*64, b = blockIdx.z;
  const u16* yb = y1 + b*524288;
  #pragma unroll
  for(int it=0; it<2; ++it){
    int c2 = it*32 + (t>>3);
    int hw = (t&7)*8;
    uint4 d = *(const uint4*)&yb[(c20+c2)*4096 + hw0 + hw];
    const u16* dv = (const u16*)&d;
    #pragma unroll
    for(int j=0;j<8;j++) L[(hw+j)*72 + c2] = dv[j];
  }
  __syncthreads();
  u16* ob = x4T + b*524288;
  #pragma unroll
  for(int it=0; it<2; ++it){
    int g2 = it*256 + t;
    int hw = g2>>3, k = g2&7;
    *(uint4*)&ob[(hw0+hw)*128 + c20 + k*8] = *(const uint4*)&L[hw*72 + k*8];
  }
}

// ---------------- conv12 MFMA: y[oc][px] = relu(BN(aT @ W^T)), NCHW stores -------------------
// Block: 512 thr (8 waves = 2px x 4oc), BM=128 px, BN=256 oc (conv1 0..127 | conv2 128..255), K=256 in 4 chunks.
__global__ __launch_bounds__(512) void k_conv12m(
    const u16* __restrict__ aTg, const float* __restrict__ w1, const float* __restrict__ w2,
    const float* __restrict__ b1, const float* __restrict__ g1, const float* __restrict__ be1,
    const float* __restrict__ m1, const float* __restrict__ v1,
    const float* __restrict__ b2, const float* __restrict__ g2, const float* __restrict__ be2,
    const float* __restrict__ m2, const float* __restrict__ v2,
    u16* __restrict__ y1, u16* __restrict__ y2)
{
  __shared__ __align__(16) u16 aL[128*64];   // [px][64c], 128B rows, unit swz ^(px&7)
  __shared__ __align__(16) u16 wL[256*64];   // [oc][64c]
  __shared__ float scL[256], shL[256];
  const int tid = threadIdx.x;
  const int wv = tid>>6, l = tid&63, g = l>>4, q = l&15;
  const int wpx = wv>>2, woc = wv&3;
  const int px0 = blockIdx.x*128, b = blockIdx.y;

  if (tid < 256){
    int oc = tid, cv = oc>>7, j = oc&127;
    float bias = cv? b2[j] : b1[j];
    float gg   = cv? g2[j] : g1[j];
    float be   = cv? be2[j]: be1[j];
    float mm   = cv? m2[j] : m1[j];
    float vv   = cv? v2[j] : v1[j];
    float sc = gg / sqrtf(vv + 1e-5f);
    scL[oc] = sc;
    shL[oc] = (bias - mm)*sc + be;           // (acc+bias)*sc + (be-mm*sc)
  }

  const u16* aTb = aTg + b*1048576;
  const int spx = tid>>2, su = (tid&3)*2;    // 128 rows x units {su,su+1} of 8 -> full 64c row
  uint4 areg[2]; float4 wreg[8];
  { // prologue: stage chunk 0
    areg[0] = *(const uint4*)&aTb[(px0+spx)*256 + 0*64 + su*8];
    areg[1] = *(const uint4*)&aTb[(px0+spx)*256 + 0*64 + (su+1)*8];
    #pragma unroll
    for(int it=0; it<8; ++it){
      int ocr = it*32 + (tid>>4); int fu = tid&15;
      const float* wp = (it<4)? &w1[ocr*256] : &w2[(ocr-128)*256];
      wreg[it] = *(const float4*)&wp[0*64 + fu*4];
    }
  }

  f32x4 acc[4][4];
  #pragma unroll
  for(int m=0;m<4;m++){
    #pragma unroll
    for(int n=0;n<4;n++) acc[m][n] = (f32x4){0.f,0.f,0.f,0.f};
  }

  for(int kc=0; kc<4; ++kc){
    __syncthreads();
    *(uint4*)((char*)aL + spx*128 + (( su   ^(spx&7))<<4)) = areg[0];
    *(uint4*)((char*)aL + spx*128 + (((su+1)^(spx&7))<<4)) = areg[1];
    #pragma unroll
    for(int it=0; it<8; ++it){
      int ocr = it*32 + (tid>>4), fu = tid&15, u = fu>>1, h = fu&1;
      *(uint2*)((char*)wL + ocr*128 + ((u^(ocr&7))<<4) + h*8)
          = make_uint2(pack2(wreg[it].x, wreg[it].y), pack2(wreg[it].z, wreg[it].w));
    }
    __syncthreads();
    if (kc<3){
      areg[0] = *(const uint4*)&aTb[(px0+spx)*256 + (kc+1)*64 + su*8];
      areg[1] = *(const uint4*)&aTb[(px0+spx)*256 + (kc+1)*64 + (su+1)*8];
      #pragma unroll
      for(int it=0; it<8; ++it){
        int ocr = it*32 + (tid>>4); int fu = tid&15;
        const float* wp = (it<4)? &w1[ocr*256] : &w2[(ocr-128)*256];
        wreg[it] = *(const float4*)&wp[(kc+1)*64 + fu*4];
      }
    }
    #pragma unroll
    for(int ks=0; ks<2; ++ks){
      bf16x8 Af[4], Bf[4];
      #pragma unroll
      for(int n=0;n<4;n++)
        Af[n] = *(const bf16x8*)((char*)wL + (woc*64+n*16+q)*128 + (((ks*4+g)^(q&7))<<4));
      #pragma unroll
      for(int m=0;m<4;m++)
        Bf[m] = *(const bf16x8*)((char*)aL + (wpx*64+m*16+q)*128 + (((ks*4+g)^(q&7))<<4));
      #pragma unroll
      for(int m=0;m<4;m++){
        #pragma unroll
        for(int n=0;n<4;n++)
          acc[m][n] = __builtin_amdgcn_mfma_f32_16x16x32_bf16(Af[n], Bf[m], acc[m][n], 0,0,0);
      }
    }
  }

  // Epilogue: BOTH convs store NCHW [c][4096]+px (raw-reshape semantics depend on this!)
  u16* yb   = (woc < 2) ? (y1 + b*524288) : (y2 + b*524288);
  const int coff = (woc < 2) ? 0 : 128;
  #pragma unroll
  for(int m=0;m<4;m++){
    int px = px0 + wpx*64 + m*16 + q;
    #pragma unroll
    for(int n=0;n<4;n++){
      #pragma unroll
      for(int e=0;e<4;e++){
        int oc = woc*64 + n*16 + g*4 + e;
        yb[(oc - coff)*4096 + px] = f2bf(fmaxf(acc[m][n][e]*scL[oc] + shL[oc], 0.f));
      }
    }
  }
}

// ---------------- pool: maxpool 3x3 s2 p1 on y2 NCHW -> pT [pos][chan], x3T [j][k] -----------
__global__ __launch_bounds__(256) void k_pool(const u16* __restrict__ y2,
                                              u16* __restrict__ pTg, u16* __restrict__ x3Tg){
  int idx = blockIdx.x*256 + threadIdx.x;
  int b = idx>>17, rem = idx & 131071;
  int c = rem>>10, pos = rem&1023;
  int oh = pos>>5, ow = pos&31;
  const u16* base = y2 + b*524288 + c*4096;
  float mx = -1e30f;
  #pragma unroll
  for(int dh=-1; dh<=1; ++dh){
    int ih = 2*oh+dh;
    if ((unsigned)ih < 64u){
      #pragma unroll
      for(int dw=-1; dw<=1; ++dw){
        int iw = 2*ow+dw;
        if((unsigned)iw<64u) mx = fmaxf(mx, bf2f(base[ih*64+iw]));
      }
    }
  }
  u16 v = f2bf(mx);
  pTg[b*131072 + pos*128 + c] = v;               // X2^T: [pos][chan]
  int f = c*1024 + pos;                          // raw flat idx of p
  x3Tg[b*131072 + (f&127)*1024 + (f>>7)] = v;    // X3^T: [j][k], X3[k][j]=p_flat[k*128+j]
}

// ---------------- attention (verified round 5): raw-view flash MFMA, O over y1 ---------------
__global__ __launch_bounds__(256) void k_attn_mfma(u16* __restrict__ y1,
    const u16* __restrict__ pTg, const u16* __restrict__ x3Tg)
{
  __shared__ __align__(16) u16 qT[64*128];
  __shared__ __align__(16) u16 kT[64*128];
  __shared__ __align__(16) u16 vT[128*64];
  __shared__ __align__(16) u16 pS[4][1024];

  const int tid = threadIdx.x, w = tid>>6, l = tid&63;
  const int g = l>>4, q = l&15;
  const int b = blockIdx.y;
  const int R0 = blockIdx.x*64;
  u16* y1b = y1 + b*524288;
  const u16* pTb = pTg + b*131072;
  const u16* vTb = x3Tg + b*131072;

  #pragma unroll
  for (int it=0; it<4; ++it){
    int idx = it*256 + tid;
    int row = idx>>4, c16 = idx&15;
    uint4 d = *(const uint4*)(y1b + (R0+row)*128 + c16*8);
    *(uint4*)((char*)qT + row*256 + ((c16 ^ (row&15))<<4)) = d;
  }
  __syncthreads();

  bf16x8 qf[4];
  #pragma unroll
  for (int kk=0; kk<4; ++kk)
    qf[kk] = *(const bf16x8*)((char*)qT + (w*16+q)*256 + (((kk*4+g) ^ q)<<4));

  f32x4 O[8];
  #pragma unroll
  for (int t=0;t<8;t++) O[t] = (f32x4){0.f,0.f,0.f,0.f};
  float m = -3.0e38f, s = 0.f;

  for (int ch=0; ch<16; ++ch){
    const int kv0 = ch*64;
    uint4 kreg[4], vreg[4];
    #pragma unroll
    for (int it=0; it<4; ++it){
      int idx = it*256 + tid;
      kreg[it] = *(const uint4*)(pTb + (kv0 + (idx>>4))*128 + (idx&15)*8);
      vreg[it] = *(const uint4*)(vTb + (idx>>3)*1024 + kv0 + (idx&7)*8);
    }
    __syncthreads();
    #pragma unroll
    for (int it=0; it<4; ++it){
      int idx = it*256 + tid;
      int row = idx>>4, c16 = idx&15;
      *(uint4*)((char*)kT + row*256 + ((c16 ^ (row&15))<<4)) = kreg[it];
      int vr = idx>>3, vc = idx&7;
      *(uint4*)((char*)vT + vr*128 + ((vc ^ (vr&7))<<4)) = vreg[it];
    }
    __syncthreads();

    f32x4 st[4];
    #pragma unroll
    for (int n=0;n<4;n++) st[n] = (f32x4){0.f,0.f,0.f,0.f};
    #pragma unroll
    for (int kk=0; kk<4; ++kk){
      #pragma unroll
      for (int n=0;n<4;n++){
        bf16x8 kf = *(const bf16x8*)((char*)kT + (n*16+q)*256 + (((kk*4+g) ^ q)<<4));
        st[n] = __builtin_amdgcn_mfma_f32_16x16x32_bf16(kf, qf[kk], st[n], 0,0,0);
      }
    }

    float cmax = st[0][0];
    #pragma unroll
    for(int n=0;n<4;n++){
      #pragma unroll
      for(int e=0;e<4;e++) cmax = fmaxf(cmax, st[n][e]);
    }
    cmax = fmaxf(cmax, __shfl_xor(cmax,16,64));
    cmax = fmaxf(cmax, __shfl_xor(cmax,32,64));
    float mnew = fmaxf(m, cmax);
    float corr = __expf(m - mnew);
    m = mnew;
    float psum = 0.f;
    #pragma unroll
    for(int n=0;n<4;n++){
      #pragma unroll
      for(int e=0;e<4;e++){ float t_ = __expf(st[n][e]-m); st[n][e]=t_; psum += t_; }
    }
    psum += __shfl_xor(psum,16,64);
    psum += __shfl_xor(psum,32,64);
    s = s*corr + psum;

    float cO[4];
    #pragma unroll
    for(int e=0;e<4;e++) cO[e] = __shfl(corr, g*4+e, 64);
    #pragma unroll
    for(int t=0;t<8;t++){
      #pragma unroll
      for(int e=0;e<4;e++) O[t][e] *= cO[e];
    }

    u16* pSw = pS[w];
    #pragma unroll
    for(int n=0;n<4;n++){
      u32 lo = pack2(st[n][0], st[n][1]);
      u32 hi = pack2(st[n][2], st[n][3]);
      *(uint2*)((char*)pSw + q*128 + (((n*4+g) ^ q)<<3)) = make_uint2(lo,hi);
    }

    #pragma unroll
    for(int kk2=0; kk2<2; ++kk2){
      int kv4a = kk2*8 + g*2;
      uint2 A0 = *(const uint2*)((char*)pSw + q*128 + (((kv4a  ) ^ q)<<3));
      uint2 A1 = *(const uint2*)((char*)pSw + q*128 + (((kv4a+1) ^ q)<<3));
      uint4 pa4 = make_uint4(A0.x, A0.y, A1.x, A1.y);
      bf16x8 pf = *(bf16x8*)&pa4;
      #pragma unroll
      for(int t=0;t<8;t++){
        bf16x8 vf = *(const bf16x8*)((char*)vT + (t*16+q)*128 + (((kk2*4+g) ^ (q&7))<<4));
        O[t] = __builtin_amdgcn_mfma_f32_16x16x32_bf16(pf, vf, O[t], 0,0,0);
      }
    }
  }

  float si[4];
  #pragma unroll
  for(int e=0;e<4;e++) si[e] = 1.0f / __shfl(s, g*4+e, 64);
  u16* ob = y1b + R0*128;
  #pragma unroll
  for(int t=0;t<8;t++){
    #pragma unroll
    for(int e=0;e<4;e++){
      int grow = w*16 + g*4 + e;
      ob[grow*128 + t*16 + q] = f2bf(O[t][e]*si[e]);
    }
  }
}

// ---------------- conv3 MFMA + BN + ReLU + residual -> out f32 NCHW --------------------------
__global__ __launch_bounds__(512) void k_conv3m(
    const u16* __restrict__ x4T, const float* __restrict__ w3,
    const float* __restrict__ b3, const float* __restrict__ g3, const float* __restrict__ be3,
    const float* __restrict__ m3, const float* __restrict__ v3,
    const float* __restrict__ a,  float* __restrict__ out)
{
  __shared__ __align__(16) u16 xL[128*64];
  __shared__ __align__(16) u16 wL[256*64];
  __shared__ float scL[256], shL[256];
  const int tid = threadIdx.x;
  const int wv = tid>>6, l = tid&63, g = l>>4, q = l&15;
  const int wpx = wv>>2, woc = wv&3;
  const int hw0 = blockIdx.x*128, b = blockIdx.y;

  if (tid < 256){
    int oc = tid;
    float sc = g3[oc] / sqrtf(v3[oc] + 1e-5f);
    scL[oc] = sc;
    shL[oc] = (b3[oc] - m3[oc])*sc + be3[oc];
  }

  const u16* xb = x4T + b*524288;
  const int shw = tid>>2, su = (tid&3)*2;    // full-row staging: units {su, su+1}
  uint4 xreg[2]; float4 wreg[8];
  {
    xreg[0] = *(const uint4*)&xb[(hw0+shw)*128 + 0*64 + su*8];
    xreg[1] = *(const uint4*)&xb[(hw0+shw)*128 + 0*64 + (su+1)*8];
    #pragma unroll
    for(int it=0; it<8; ++it){
      int ocr = it*32 + (tid>>4); int fu = tid&15;
      wreg[it] = *(const float4*)&w3[ocr*128 + 0*64 + fu*4];
    }
  }

  f32x4 acc[4][4];
  #pragma unroll
  for(int m=0;m<4;m++){
    #pragma unroll
    for(int n=0;n<4;n++) acc[m][n] = (f32x4){0.f,0.f,0.f,0.f};
  }

  for(int kc=0; kc<2; ++kc){
    __syncthreads();
    *(uint4*)((char*)xL + shw*128 + (( su   ^(shw&7))<<4)) = xreg[0];
    *(uint4*)((char*)xL + shw*128 + (((su+1)^(shw&7))<<4)) = xreg[1];
    #pragma unroll
    for(int it=0; it<8; ++it){
      int ocr = it*32 + (tid>>4), fu = tid&15, u = fu>>1, h = fu&1;
      *(uint2*)((char*)wL + ocr*128 + ((u^(ocr&7))<<4) + h*8)
          = make_uint2(pack2(wreg[it].x, wreg[it].y), pack2(wreg[it].z, wreg[it].w));
    }
    __syncthreads();
    if (kc<1){
      xreg[0] = *(const uint4*)&xb[(hw0+shw)*128 + 64 + su*8];
      xreg[1] = *(const uint4*)&xb[(hw0+shw)*128 + 64 + (su+1)*8];
      #pragma unroll
      for(int it=0; it<8; ++it){
        int ocr = it*32 + (tid>>4); int fu = tid&15;
        wreg[it] = *(const float4*)&w3[ocr*128 + 64 + fu*4];
      }
    }
    #pragma unroll
    for(int ks=0; ks<2; ++ks){
      bf16x8 Af[4], Bf[4];
      #pragma unroll
      for(int n=0;n<4;n++)
        Af[n] = *(const bf16x8*)((char*)wL + (woc*64+n*16+q)*128 + (((ks*4+g)^(q&7))<<4));
      #pragma unroll
      for(int m=0;m<4;m++)
        Bf[m] = *(const bf16x8*)((char*)xL + (wpx*64+m*16+q)*128 + (((ks*4+g)^(q&7))<<4));
      #pragma unroll
      for(int m=0;m<4;m++){
        #pragma unroll
        for(int n=0;n<4;n++)
          acc[m][n] = __builtin_amdgcn_mfma_f32_16x16x32_bf16(Af[n], Bf[m], acc[m][n], 0,0,0);
      }
    }
  }

  const float* ab = a + b*1048576;
  float* ob = out + b*1048576;
  #pragma unroll
  for(int m=0;m<4;m++){
    int hw = hw0 + wpx*64 + m*16 + q;
    #pragma unroll
    for(int n=0;n<4;n++){
      #pragma unroll
      for(int e=0;e<4;e++){
        int oc = woc*64 + n*16 + g*4 + e;
        int gi = oc*4096 + hw;
        ob[gi] = fmaxf(acc[m][n][e]*scL[oc] + shL[oc], 0.f) + ab[gi];
      }
    }
  }
}

extern "C" void kernel_launch(void* const* d_in, const int* in_sizes, int n_in,
                              void* d_out, int out_size, void* d_ws, size_t ws_size,
                              hipStream_t stream)
{
  const float* a   = (const float*)d_in[0];
  const float* w1  = (const float*)d_in[1];
  const float* b1  = (const float*)d_in[2];
  const float* g1  = (const float*)d_in[3];
  const float* be1 = (const float*)d_in[4];
  const float* m1  = (const float*)d_in[5];
  const float* v1  = (const float*)d_in[6];
  const float* w2  = (const float*)d_in[7];
  const float* b2  = (const float*)d_in[8];
  const float* g2  = (const float*)d_in[9];
  const float* be2 = (const float*)d_in[10];
  const float* m2  = (const float*)d_in[11];
  const float* v2  = (const float*)d_in[12];
  const float* w3  = (const float*)d_in[13];
  const float* b3  = (const float*)d_in[14];
  const float* g3  = (const float*)d_in[15];
  const float* be3 = (const float*)d_in[16];
  const float* m3  = (const float*)d_in[17];
  const float* v3  = (const float*)d_in[18];
  float* out = (float*)d_out;

  u16* d16  = (u16*)d_out;
  u16* aTg  = d16;                      // 8,388,608 u16 (dead after conv12m)
  u16* pT   = d16;                      // 1,048,576 u16 (reuses aTg space, after conv12m)
  u16* x3T  = d16 + 1048576;            // 1,048,576 u16
  u16* y2   = d16 + 8388608;            // 4,194,304 u16 (dead after pool)
  u16* y1   = d16 + 12582912;           // 4,194,304 u16 (dead after T2)
  u16* x4T  = (u16*)d_ws;               // 4,194,304 u16 (8 MB)

  k_t1      <<<dim3(64,4,8), 256, 0, stream>>>(a, aTg);
  k_conv12m <<<dim3(32,8),   512, 0, stream>>>(aTg,w1,w2,b1,g1,be1,m1,v1,b2,g2,be2,m2,v2,y1,y2);
  k_pool    <<<dim3(4096),   256, 0, stream>>>(y2, pT, x3T);
  k_attn_mfma<<<dim3(64,8),  256, 0, stream>>>(y1, pT, x3T);
  k_t2      <<<dim3(64,2,8), 256, 0, stream>>>(y1, x4T);
  k_conv3m  <<<dim3(32,8),   512, 0, stream>>>(x4T,w3,b3,g3,be3,m3,v3,a,out);
}